// Round 1
// baseline (111.707 us; speedup 1.0000x reference)
//
#include <hip/hip_runtime.h>

#define NB 16
#define NL 1024
#define ND 64
#define NW 20
#define THR 0.3f

// One block per (b,l). 256 threads. Each thread computes a 4x4 tile of the
// 64x64 correlation/adjacency matrix for its (b,l).
__global__ __launch_bounds__(256) void dyn_corr_kernel(
    const float* __restrict__ x, float* __restrict__ out)
{
    const int bl = blockIdx.x;          // 0..16383
    const int b  = bl >> 10;            // / NL
    const int l  = bl & (NL - 1);
    const int t  = threadIdx.x;

    __shared__ float win[NW][ND];       // 20*64*4 = 5120 B, centered in place
    __shared__ float meanv[ND];
    __shared__ float diag[ND];          // cov[d][d]

    const float* xb = x + ((size_t)b * NL) * ND;

    // --- stage window (rows l-19..l, zero-padded before l=0), coalesced ---
    #pragma unroll
    for (int i = 0; i < 5; ++i) {
        int idx  = t + i * 256;         // 0..1279
        int w    = idx >> 6;
        int d    = idx & 63;
        int lsrc = l - (NW - 1) + w;
        win[w][d] = (lsrc >= 0) ? xb[(size_t)lsrc * ND + d] : 0.0f;
    }
    __syncthreads();

    // --- per-feature mean over the 20-row window (padded zeros included,
    //     exactly as the reference's jnp.pad does) ---
    if (t < ND) {
        float s = 0.0f;
        #pragma unroll
        for (int w = 0; w < NW; ++w) s += win[w][t];
        meanv[t] = s * (1.0f / NW);
    }
    __syncthreads();

    // --- center in place (padded rows become -mean, as in reference) ---
    #pragma unroll
    for (int i = 0; i < 5; ++i) {
        int idx = t + i * 256;
        int w   = idx >> 6;
        int d   = idx & 63;
        win[w][d] -= meanv[d];
    }
    __syncthreads();

    // --- 4x4 cov tile per thread: rows d0..d0+3, cols e0..e0+3 ---
    const int tr = t >> 4;              // 0..15
    const int tc = t & 15;              // 0..15
    const int d0 = tr << 2;
    const int e0 = tc << 2;

    float acc[4][4] = {};
    #pragma unroll
    for (int w = 0; w < NW; ++w) {
        float4 cdv = *(const float4*)&win[w][d0];   // broadcast across 16 lanes
        float4 cev = *(const float4*)&win[w][e0];   // 16 distinct b128 / wave
        float cd[4] = {cdv.x, cdv.y, cdv.z, cdv.w};
        float ce[4] = {cev.x, cev.y, cev.z, cev.w};
        #pragma unroll
        for (int i = 0; i < 4; ++i)
            #pragma unroll
            for (int j = 0; j < 4; ++j)
                acc[i][j] = fmaf(cd[i], ce[j], acc[i][j]);
    }

    const float inv = 1.0f / (NW - 1);

    // diagonal tiles publish cov[d][d]
    if (tr == tc) {
        #pragma unroll
        for (int i = 0; i < 4; ++i) diag[d0 + i] = acc[i][i] * inv;
    }
    __syncthreads();

    float sd[4], se[4];
    #pragma unroll
    for (int i = 0; i < 4; ++i) {
        sd[i] = sqrtf(diag[d0 + i]);
        se[i] = sqrtf(diag[e0 + i]);
    }

    // --- normalize + relu(|corr| - 0.3), float4 stores ---
    float* ob = out + (size_t)bl * (ND * ND);
    #pragma unroll
    for (int i = 0; i < 4; ++i) {
        float4 o;
        float v;
        v = fabsf(__fdividef(acc[i][0] * inv, sd[i] * se[0] + 1e-8f)) - THR; o.x = fmaxf(v, 0.0f);
        v = fabsf(__fdividef(acc[i][1] * inv, sd[i] * se[1] + 1e-8f)) - THR; o.y = fmaxf(v, 0.0f);
        v = fabsf(__fdividef(acc[i][2] * inv, sd[i] * se[2] + 1e-8f)) - THR; o.z = fmaxf(v, 0.0f);
        v = fabsf(__fdividef(acc[i][3] * inv, sd[i] * se[3] + 1e-8f)) - THR; o.w = fmaxf(v, 0.0f);
        *(float4*)&ob[(d0 + i) * ND + e0] = o;
    }
}

extern "C" void kernel_launch(void* const* d_in, const int* in_sizes, int n_in,
                              void* d_out, int out_size, void* d_ws, size_t ws_size,
                              hipStream_t stream) {
    const float* x = (const float*)d_in[0];
    float* out = (float*)d_out;
    dim3 grid(NB * NL);
    dim3 block(256);
    hipLaunchKernelGGL(dyn_corr_kernel, grid, block, 0, stream, x, out);
}